// Round 2
// baseline (374.115 us; speedup 1.0000x reference)
//
#include <hip/hip_runtime.h>
#include <hip/hip_bf16.h>

#define BATCH 8
#define SEQ   2048
#define DIM   128
#define NROWS 16384                       // BATCH*SEQ
#define THETA_SPAN 22.62741699796952f     // 2*sqrt(128) = 1/c ; c^2 = 1/512

typedef __bf16    bf16x8   __attribute__((ext_vector_type(8)));
typedef float     floatx4  __attribute__((ext_vector_type(4)));
typedef _Float16  half2v   __attribute__((ext_vector_type(2)));

static __device__ __forceinline__ unsigned short f2bf(float v) {
    union { __hip_bfloat16 h; unsigned short u; } c;
    c.h = __float2bfloat16(v);
    return c.u;
}
static __device__ __forceinline__ float bf2f(unsigned short u) {
    union { unsigned int i; float f; } c;
    c.i = (unsigned int)u << 16;
    return c.f;
}
static __device__ __forceinline__ unsigned int f2h2(float a, float b) {
    union { _Float16 h; unsigned short u; } ca, cb;
    ca.h = (_Float16)a;
    cb.h = (_Float16)b;
    return (unsigned int)ca.u | ((unsigned int)cb.u << 16);
}

#if __has_builtin(__builtin_amdgcn_fdot2)
static __device__ __forceinline__ float fdot2acc(half2v a, half2v b, float c) {
    return __builtin_amdgcn_fdot2(a, b, c, false);
}
#else
static __device__ __forceinline__ float fdot2acc(half2v a, half2v b, float c) {
    return fmaf((float)a.y, (float)b.y, fmaf((float)a.x, (float)b.x, c));
}
#endif

// ---------------------------------------------------------------------------
// MFMA-based Q/K projection (unchanged — verified).
// ---------------------------------------------------------------------------
__global__ void __launch_bounds__(256, 2)
proj_qk(const float* __restrict__ xq, const float* __restrict__ xn,
        const float* __restrict__ Wq, const float* __restrict__ bq,
        const float* __restrict__ Wk, const float* __restrict__ bk,
        unsigned short* __restrict__ Qb, unsigned short* __restrict__ Kb) {
    const int isK = blockIdx.y;
    const float* __restrict__ X    = isK ? xn : xq;
    const float* __restrict__ W    = isK ? Wk : Wq;
    const float* __restrict__ bias = isK ? bk : bq;

    __shared__ __align__(16) unsigned short SM[34816];
    unsigned short* XH = SM;            // 64 x 136
    unsigned short* XL = SM + 8704;     // 64 x 136
    unsigned short* WW = SM + 17408;    // 128 x 136

    const int tid  = threadIdx.x;
    const int lane = tid & 63;
    const int wv   = tid >> 6;          // 0..3
    const int l4   = lane & 15;
    const int quad = lane >> 4;         // 0..3
    const int row0 = blockIdx.x * 64;

    // ---- stage X (64x128 f32 -> bf16 hi+lo), coalesced float4 reads ----
#pragma unroll
    for (int i = 0; i < 8; ++i) {
        const int g  = tid + 256 * i;          // g < 2048
        const int r  = g >> 5;
        const int c4 = g & 31;
        const float4 xv = *reinterpret_cast<const float4*>(
            X + (size_t)(row0 + r) * DIM + 4 * c4);
        union { ushort2 v[2]; unsigned short u[4]; } hh, ll;
        const float xf[4] = {xv.x, xv.y, xv.z, xv.w};
#pragma unroll
        for (int j = 0; j < 4; ++j) {
            const unsigned short h = f2bf(xf[j]);
            hh.u[j] = h;
            ll.u[j] = f2bf(xf[j] - bf2f(h));
        }
        *reinterpret_cast<uint2*>(&XH[r * 136 + 4 * c4]) =
            *reinterpret_cast<uint2*>(hh.u);
        *reinterpret_cast<uint2*>(&XL[r * 136 + 4 * c4]) =
            *reinterpret_cast<uint2*>(ll.u);
    }
    // ---- stage W (128x128 f32 -> bf16), coalesced ----
#pragma unroll
    for (int i = 0; i < 16; ++i) {
        const int g  = tid + 256 * i;          // g < 4096
        const int d  = g >> 5;
        const int c4 = g & 31;
        const float4 wvv = *reinterpret_cast<const float4*>(
            W + (size_t)d * DIM + 4 * c4);
        union { uint2 v; unsigned short u[4]; } pw;
        pw.u[0] = f2bf(wvv.x); pw.u[1] = f2bf(wvv.y);
        pw.u[2] = f2bf(wvv.z); pw.u[3] = f2bf(wvv.w);
        *reinterpret_cast<uint2*>(&WW[d * 136 + 4 * c4]) = pw.v;
    }
    __syncthreads();

    // ---- MFMA: acc[mt][reg] = value of (row = wv*16+l4, d = mt*16+quad*4+reg)
    floatx4 acc[8];
    const floatx4 zerov = {};
#pragma unroll
    for (int mt = 0; mt < 8; ++mt) acc[mt] = zerov;

#pragma unroll
    for (int kt = 0; kt < 4; ++kt) {
        const int koff = kt * 32 + quad * 8;
        const bf16x8 xh = *reinterpret_cast<const bf16x8*>(
            &XH[(wv * 16 + l4) * 136 + koff]);
        const bf16x8 xl = *reinterpret_cast<const bf16x8*>(
            &XL[(wv * 16 + l4) * 136 + koff]);
#pragma unroll
        for (int mt = 0; mt < 8; ++mt) {
            const bf16x8 wf = *reinterpret_cast<const bf16x8*>(
                &WW[(mt * 16 + l4) * 136 + koff]);
            acc[mt] = __builtin_amdgcn_mfma_f32_16x16x32_bf16(wf, xh, acc[mt], 0, 0, 0);
            acc[mt] = __builtin_amdgcn_mfma_f32_16x16x32_bf16(wf, xl, acc[mt], 0, 0, 0);
        }
    }

    // ---- epilogue: +bias, round once to bf16, pack into XH plane (own rows)
    const int erow = wv * 16 + l4;      // this lane's output row
#pragma unroll
    for (int mt = 0; mt < 8; ++mt) {
        const float4 bv = *reinterpret_cast<const float4*>(bias + mt * 16 + quad * 4);
        const float bf[4] = {bv.x, bv.y, bv.z, bv.w};
        union { uint2 v; unsigned short u[4]; } hh;
#pragma unroll
        for (int r = 0; r < 4; ++r) hh.u[r] = f2bf(acc[mt][r] + bf[r]);
        *reinterpret_cast<uint2*>(&XH[erow * 136 + mt * 16 + quad * 4]) = hh.v;
    }
    __syncthreads();

    // ---- readback + coalesced global stores (verified layouts) ----
    const int l    = tid & 15;
    const int kthi = tid >> 4;          // 0..15
    if (!isK) {
#pragma unroll
        for (int rr = 0; rr < 4; ++rr) {
            const int row = l + 16 * rr;
            const uint4 ph = *reinterpret_cast<const uint4*>(&XH[row * 136 + kthi * 8]);
            const size_t base = ((size_t)kthi * NROWS + row0 + row) * 8;
            *reinterpret_cast<uint4*>(Qb + base) = ph;
        }
    } else {
#pragma unroll
        for (int rr = 0; rr < 4; ++rr) {
            const int row = l + 16 * rr;
            const int grow = row0 + row;
            const int b    = grow >> 11;
            const int key  = grow & (SEQ - 1);
            const uint4 pk = *reinterpret_cast<const uint4*>(&XH[row * 136 + kthi * 8]);
            const size_t base = (((size_t)(b * 16) + kthi) * SEQ + key) * 8;
            *reinterpret_cast<uint4*>(Kb + base) = pk;
        }
    }
}

// ---------------------------------------------------------------------------
// FUSED scores + entmax. Verified math + LDS subplane layout. NEW this round:
// each block processes TWO adjacent 16-row tiles sequentially (grid halves to
// 512). Tile 1 re-reads exactly the K lines tile 0 just fetched, on the SAME
// CU -> tile-1 K reads hit the XCD's L2 irrespective of dispatch mapping.
// K traffic to L3/HBM: 512 MB -> ~256 MB. LDS unchanged (65792 B, 2 blk/CU,
// 4 waves/SIMD), per-wave code unchanged, batch->XCD pinning retained so
// co-resident blocks share one 512 KB K slice inside the 4 MiB L2.
// Cost: +2 barriers/block, doubled block lifetime.
// ---------------------------------------------------------------------------
__global__ void __launch_bounds__(512, 4)
attn_fused(const __bf16* __restrict__ Qb, const __bf16* __restrict__ Kb,
           float* __restrict__ out) {
    __shared__ unsigned int SW[8 * 2056];
    const int tid  = threadIdx.x;
    const int wv   = tid >> 6;              // 0..7
    const int lane = tid & 63;
    const int l4   = lane & 15;
    const int quad = lane >> 4;             // 0..3
    const int b    = blockIdx.x & 7;        // batch == XCD (round-robin dispatch)
    const int rb   = blockIdx.x >> 3;       // 0..63: 32-row group within batch
    const int key0 = wv * 256;

    // K addressing is row0-independent: hoist once; tile 1 reuses identical
    // addresses (the L2-reuse mechanism).
    const size_t kbase = (((size_t)(b * 16) + quad) * SEQ + key0 + l4) * 8;
    const size_t kstep = (size_t)4 * SEQ * 8;
    const size_t qstep = (size_t)4 * NROWS * 8;

    const int g  = wv >> 1;                 // rowgroup 0..3
    const int sp = wv & 1;                  // rows 4g+2sp+{0,1}
    const unsigned int* Sw = &SW[(2 * g + sp) * 2056];

    for (int tile = 0; tile < 2; ++tile) {
        const int row0 = (b << 11) + (rb << 5) + (tile << 4);

        // ---------------- phase 1: MFMA scores -> LDS subplanes ------------
        {
            floatx4 acc[16];
            const floatx4 zerov = {};
#pragma unroll
            for (int t = 0; t < 16; ++t) acc[t] = zerov;

            const size_t qbase = ((size_t)quad * NROWS + row0 + l4) * 8;

#pragma unroll
            for (int kt = 0; kt < 4; ++kt) {
                const bf16x8 ah = *reinterpret_cast<const bf16x8*>(Qb + qbase + kt * qstep);
                const __bf16* kc = Kb + kbase + kt * kstep;
#pragma unroll
                for (int t = 0; t < 16; ++t) {
                    const bf16x8 bkv = *reinterpret_cast<const bf16x8*>(kc + (size_t)t * 128);
                    acc[t] = __builtin_amdgcn_mfma_f32_16x16x32_bf16(ah, bkv, acc[t], 0, 0, 0);
                }
            }
            // C/D: col = l4 (key), row = quad*4 + reg. dword0 = rows {4q,4q+1},
            // dword1 = rows {4q+2,4q+3} -> planes 2q and 2q+1 at [key].
#pragma unroll
            for (int t = 0; t < 16; ++t) {
                const int key = key0 + t * 16 + l4;
                SW[(2 * quad + 0) * 2056 + key] = f2h2(acc[t][0], acc[t][1]);
                SW[(2 * quad + 1) * 2056 + key] = f2h2(acc[t][2], acc[t][3]);
            }
        }
        __syncthreads();

        // ---------------- phase 2: entmax, 2 rows per wave -----------------
        unsigned int raw[32];
#pragma unroll
        for (int c = 0; c < 32; ++c) raw[c] = Sw[c * 64 + lane];   // stride-1: no conflict
        __syncthreads();   // LDS consumed -> next tile's phase 1 may overwrite

        // split into the two sub-rows' f16x2 key-pair vectors
        half2v z0[16], z1[16];
#pragma unroll
        for (int i = 0; i < 16; ++i) {
            union { unsigned int u; half2v h; } c0, c1;
            c0.u = __builtin_amdgcn_perm(raw[2 * i + 1], raw[2 * i], 0x05040100u);
            c1.u = __builtin_amdgcn_perm(raw[2 * i + 1], raw[2 * i], 0x07060302u);
            z0[i] = c0.h;
            z1[i] = c1.h;
        }

        const half2v hzero = {(_Float16)0.0f, (_Float16)0.0f};
        const half2v hone  = {(_Float16)1.0f, (_Float16)1.0f};

        // row maxes (two independent chains)
        float m0 = -1e30f, m1 = -1e30f;
#pragma unroll
        for (int i = 0; i < 16; ++i) {
            m0 = fmaxf(m0, fmaxf((float)z0[i].x, (float)z0[i].y));
            m1 = fmaxf(m1, fmaxf((float)z1[i].x, (float)z1[i].y));
        }
#pragma unroll
        for (int off = 32; off >= 1; off >>= 1) {
            m0 = fmaxf(m0, __shfl_xor(m0, off, 64));
            m1 = fmaxf(m1, __shfl_xor(m1, off, 64));
        }

        // Newton: th += (f - 512)/(2g); monotone from the left, 7 iterations
        float th0 = m0 - THETA_SPAN;
        float th1 = m1 - THETA_SPAN;
        for (int it = 0; it < 7; ++it) {
            const _Float16 t0h = (_Float16)th0;
            const _Float16 t1h = (_Float16)th1;
            const half2v n0 = {(_Float16)-t0h, (_Float16)-t0h};
            const half2v n1 = {(_Float16)-t1h, (_Float16)-t1h};
            float f0 = 0.0f, f1 = 0.0f, g0 = 0.0f, g1 = 0.0f;
#pragma unroll
            for (int i = 0; i < 16; ++i) {
                half2v d0 = z0[i] + n0;
                half2v d1 = z1[i] + n1;
                d0 = __builtin_elementwise_max(d0, hzero);
                d1 = __builtin_elementwise_max(d1, hzero);
                f0 = fdot2acc(d0, d0, f0);
                f1 = fdot2acc(d1, d1, f1);
                g0 = fdot2acc(d0, hone, g0);
                g1 = fdot2acc(d1, hone, g1);
            }
#pragma unroll
            for (int off = 32; off >= 1; off >>= 1) {
                f0 += __shfl_xor(f0, off, 64);
                f1 += __shfl_xor(f1, off, 64);
                g0 += __shfl_xor(g0, off, 64);
                g1 += __shfl_xor(g1, off, 64);
            }
            th0 += (f0 - 512.0f) / (2.0f * g0);
            th1 += (f1 - 512.0f) / (2.0f * g1);
        }

        // epilogue: p = max(s-th,0)^2 / 512, nontemporal f32 coalesced stores
        float* o0 = out + (size_t)(row0 + 4 * g + 2 * sp + 0) * SEQ + lane;
        float* o1 = out + (size_t)(row0 + 4 * g + 2 * sp + 1) * SEQ + lane;
#pragma unroll
        for (int i = 0; i < 16; ++i) {
            const float a0 = fmaxf((float)z0[i].x - th0, 0.0f);
            const float a1 = fmaxf((float)z0[i].y - th0, 0.0f);
            const float b0 = fmaxf((float)z1[i].x - th1, 0.0f);
            const float b1 = fmaxf((float)z1[i].y - th1, 0.0f);
            __builtin_nontemporal_store(a0 * a0 * (1.0f / 512.0f), o0 + (size_t)(2 * i) * 64);
            __builtin_nontemporal_store(a1 * a1 * (1.0f / 512.0f), o0 + (size_t)(2 * i + 1) * 64);
            __builtin_nontemporal_store(b0 * b0 * (1.0f / 512.0f), o1 + (size_t)(2 * i) * 64);
            __builtin_nontemporal_store(b1 * b1 * (1.0f / 512.0f), o1 + (size_t)(2 * i + 1) * 64);
        }
    }
}

// ---------------------------------------------------------------------------
extern "C" void kernel_launch(void* const* d_in, const int* in_sizes, int n_in,
                              void* d_out, int out_size, void* d_ws, size_t ws_size,
                              hipStream_t stream) {
    const float* x_c = (const float*)d_in[0];
    const float* x_n = (const float*)d_in[1];
    const float* Wq  = (const float*)d_in[2];
    const float* bq  = (const float*)d_in[3];
    const float* Wk  = (const float*)d_in[4];
    const float* bk  = (const float*)d_in[5];
    float* out = (float*)d_out;

    char* ws = (char*)d_ws;
    unsigned short* Qbl = (unsigned short*)ws;                        // 4 MB
    unsigned short* Kbl = (unsigned short*)(ws + ((size_t)4 << 20));  // 4 MB

    proj_qk<<<dim3(NROWS / 64, 2), 256, 0, stream>>>(
        x_c, x_n, Wq, bq, Wk, bk, Qbl, Kbl);
    attn_fused<<<NROWS / 32, 512, 0, stream>>>(
        (const __bf16*)Qbl, (const __bf16*)Kbl, out);
}

// Round 3
// 200.256 us; speedup vs baseline: 1.8682x; 1.8682x over previous
//
#include <hip/hip_runtime.h>
#include <hip/hip_bf16.h>

#define BATCH 8
#define SEQ   2048
#define DIM   128
#define NROWS 16384                       // BATCH*SEQ
#define THETA_SPAN 22.62741699796952f     // 2*sqrt(128) = 1/c ; c^2 = 1/512

typedef __bf16    bf16x8   __attribute__((ext_vector_type(8)));
typedef float     floatx4  __attribute__((ext_vector_type(4)));
typedef _Float16  half2v   __attribute__((ext_vector_type(2)));

static __device__ __forceinline__ unsigned short f2bf(float v) {
    union { __hip_bfloat16 h; unsigned short u; } c;
    c.h = __float2bfloat16(v);
    return c.u;
}
static __device__ __forceinline__ float bf2f(unsigned short u) {
    union { unsigned int i; float f; } c;
    c.i = (unsigned int)u << 16;
    return c.f;
}
static __device__ __forceinline__ unsigned int f2h2(float a, float b) {
    union { _Float16 h; unsigned short u; } ca, cb;
    ca.h = (_Float16)a;
    cb.h = (_Float16)b;
    return (unsigned int)ca.u | ((unsigned int)cb.u << 16);
}

#if __has_builtin(__builtin_amdgcn_fdot2)
static __device__ __forceinline__ float fdot2acc(half2v a, half2v b, float c) {
    return __builtin_amdgcn_fdot2(a, b, c, false);
}
#else
static __device__ __forceinline__ float fdot2acc(half2v a, half2v b, float c) {
    return fmaf((float)a.y, (float)b.y, fmaf((float)a.x, (float)b.x, c));
}
#endif

// ---------------------------------------------------------------------------
// MFMA-based Q/K projection (verified). Also zeroes the 8 per-XCD work
// counters used by attn_fused (stream-ordered: proj completes, L2 flushed,
// before attn dispatch starts).
// ---------------------------------------------------------------------------
__global__ void __launch_bounds__(256, 2)
proj_qk(const float* __restrict__ xq, const float* __restrict__ xn,
        const float* __restrict__ Wq, const float* __restrict__ bq,
        const float* __restrict__ Wk, const float* __restrict__ bk,
        unsigned short* __restrict__ Qb, unsigned short* __restrict__ Kb,
        unsigned int* __restrict__ cnt) {
    const int isK = blockIdx.y;
    const float* __restrict__ X    = isK ? xn : xq;
    const float* __restrict__ W    = isK ? Wk : Wq;
    const float* __restrict__ bias = isK ? bk : bq;

    __shared__ __align__(16) unsigned short SM[34816];
    unsigned short* XH = SM;            // 64 x 136
    unsigned short* XL = SM + 8704;     // 64 x 136
    unsigned short* WW = SM + 17408;    // 128 x 136

    const int tid  = threadIdx.x;
    const int lane = tid & 63;
    const int wv   = tid >> 6;          // 0..3
    const int l4   = lane & 15;
    const int quad = lane >> 4;         // 0..3
    const int row0 = blockIdx.x * 64;

    if (blockIdx.x == 0 && blockIdx.y == 0 && tid < 8) cnt[tid] = 0u;

    // ---- stage X (64x128 f32 -> bf16 hi+lo), coalesced float4 reads ----
#pragma unroll
    for (int i = 0; i < 8; ++i) {
        const int g  = tid + 256 * i;          // g < 2048
        const int r  = g >> 5;
        const int c4 = g & 31;
        const float4 xv = *reinterpret_cast<const float4*>(
            X + (size_t)(row0 + r) * DIM + 4 * c4);
        union { ushort2 v[2]; unsigned short u[4]; } hh, ll;
        const float xf[4] = {xv.x, xv.y, xv.z, xv.w};
#pragma unroll
        for (int j = 0; j < 4; ++j) {
            const unsigned short h = f2bf(xf[j]);
            hh.u[j] = h;
            ll.u[j] = f2bf(xf[j] - bf2f(h));
        }
        *reinterpret_cast<uint2*>(&XH[r * 136 + 4 * c4]) =
            *reinterpret_cast<uint2*>(hh.u);
        *reinterpret_cast<uint2*>(&XL[r * 136 + 4 * c4]) =
            *reinterpret_cast<uint2*>(ll.u);
    }
    // ---- stage W (128x128 f32 -> bf16), coalesced ----
#pragma unroll
    for (int i = 0; i < 16; ++i) {
        const int g  = tid + 256 * i;          // g < 4096
        const int d  = g >> 5;
        const int c4 = g & 31;
        const float4 wvv = *reinterpret_cast<const float4*>(
            W + (size_t)d * DIM + 4 * c4);
        union { uint2 v; unsigned short u[4]; } pw;
        pw.u[0] = f2bf(wvv.x); pw.u[1] = f2bf(wvv.y);
        pw.u[2] = f2bf(wvv.z); pw.u[3] = f2bf(wvv.w);
        *reinterpret_cast<uint2*>(&WW[d * 136 + 4 * c4]) = pw.v;
    }
    __syncthreads();

    // ---- MFMA: acc[mt][reg] = value of (row = wv*16+l4, d = mt*16+quad*4+reg)
    floatx4 acc[8];
    const floatx4 zerov = {};
#pragma unroll
    for (int mt = 0; mt < 8; ++mt) acc[mt] = zerov;

#pragma unroll
    for (int kt = 0; kt < 4; ++kt) {
        const int koff = kt * 32 + quad * 8;
        const bf16x8 xh = *reinterpret_cast<const bf16x8*>(
            &XH[(wv * 16 + l4) * 136 + koff]);
        const bf16x8 xl = *reinterpret_cast<const bf16x8*>(
            &XL[(wv * 16 + l4) * 136 + koff]);
#pragma unroll
        for (int mt = 0; mt < 8; ++mt) {
            const bf16x8 wf = *reinterpret_cast<const bf16x8*>(
                &WW[(mt * 16 + l4) * 136 + koff]);
            acc[mt] = __builtin_amdgcn_mfma_f32_16x16x32_bf16(wf, xh, acc[mt], 0, 0, 0);
            acc[mt] = __builtin_amdgcn_mfma_f32_16x16x32_bf16(wf, xl, acc[mt], 0, 0, 0);
        }
    }

    // ---- epilogue: +bias, round once to bf16, pack into XH plane (own rows)
    const int erow = wv * 16 + l4;      // this lane's output row
#pragma unroll
    for (int mt = 0; mt < 8; ++mt) {
        const float4 bv = *reinterpret_cast<const float4*>(bias + mt * 16 + quad * 4);
        const float bf[4] = {bv.x, bv.y, bv.z, bv.w};
        union { uint2 v; unsigned short u[4]; } hh;
#pragma unroll
        for (int r = 0; r < 4; ++r) hh.u[r] = f2bf(acc[mt][r] + bf[r]);
        *reinterpret_cast<uint2*>(&XH[erow * 136 + mt * 16 + quad * 4]) = hh.v;
    }
    __syncthreads();

    // ---- readback + coalesced global stores (verified layouts) ----
    const int l    = tid & 15;
    const int kthi = tid >> 4;          // 0..15
    if (!isK) {
#pragma unroll
        for (int rr = 0; rr < 4; ++rr) {
            const int row = l + 16 * rr;
            const uint4 ph = *reinterpret_cast<const uint4*>(&XH[row * 136 + kthi * 8]);
            const size_t base = ((size_t)kthi * NROWS + row0 + row) * 8;
            *reinterpret_cast<uint4*>(Qb + base) = ph;
        }
    } else {
#pragma unroll
        for (int rr = 0; rr < 4; ++rr) {
            const int row = l + 16 * rr;
            const int grow = row0 + row;
            const int b    = grow >> 11;
            const int key  = grow & (SEQ - 1);
            const uint4 pk = *reinterpret_cast<const uint4*>(&XH[row * 136 + kthi * 8]);
            const size_t base = (((size_t)(b * 16) + kthi) * SEQ + key) * 8;
            *reinterpret_cast<uint4*>(Kb + base) = pk;
        }
    }
}

// ---------------------------------------------------------------------------
// FUSED scores + entmax — round-1 body (1 tile/block, verified) with NEW
// dynamic XCD-local work claiming. Round-2 evidence: FETCH == full issued
// K-read volume -> zero cross-block L2 reuse -> the static blockIdx%8->XCD
// assumption is wrong. Here each block reads its REAL XCD (s_getreg
// HW_REG_XCC_ID, id=20) and claims a row-tile of the batch pinned to that
// XCD from per-XCD atomic counters. Claim-with-fallback over all 8 pools +
// exactly 1024 blocks => exactly-once coverage regardless of dispatch skew
// (a block only skips pool j after j's 128 tiles are all claimed), and
// correctness is independent of the s_getreg value (it only biases
// locality). Result: each XCD's L2 serves ONE 512 KB K slice -> the 512 MB
// of K re-reads become L2 hits instead of fabric traffic.
// ---------------------------------------------------------------------------
__global__ void __launch_bounds__(512, 4)
attn_fused(const __bf16* __restrict__ Qb, const __bf16* __restrict__ Kb,
           float* __restrict__ out, unsigned int* __restrict__ cnt) {
    __shared__ unsigned int SW[8 * 2056];   // planes use [0..2047]; slack at end
    const int tid  = threadIdx.x;
    const int wv   = tid >> 6;              // 0..7
    const int lane = tid & 63;
    const int l4   = lane & 15;
    const int quad = lane >> 4;             // 0..3

    // ---- claim a (batch, row-tile) on this block's actual XCD ----
    if (tid == 0) {
        unsigned int x;
        asm volatile("s_getreg_b32 %0, hwreg(20, 0, 8)" : "=s"(x));  // HW_REG_XCC_ID
        x &= 7u;
        unsigned int bb = x, rr = 0u;
        for (int t = 0; t < 8; ++t) {
            bb = (x + (unsigned)t) & 7u;
            rr = atomicAdd(&cnt[bb], 1u);
            if (rr < 128u) break;
        }
        SW[16440] = (bb << 8) | (rr & 255u);   // never touched by score planes
    }
    __syncthreads();
    const unsigned int asg = SW[16440];
    const int b    = (int)(asg >> 8);
    const int rb   = (int)(asg & 255u);
    const int row0 = (b << 11) + (rb << 4);
    const int key0 = wv * 256;

    // ---------------- phase 1: MFMA scores -> LDS subplanes ----------------
    {
        floatx4 acc[16];
        const floatx4 zerov = {};
#pragma unroll
        for (int t = 0; t < 16; ++t) acc[t] = zerov;

        const size_t qbase = ((size_t)quad * NROWS + row0 + l4) * 8;
        const size_t kbase = (((size_t)(b * 16) + quad) * SEQ + key0 + l4) * 8;
        const size_t qstep = (size_t)4 * NROWS * 8;   // kt -> kt+1
        const size_t kstep = (size_t)4 * SEQ * 8;

#pragma unroll
        for (int kt = 0; kt < 4; ++kt) {
            const bf16x8 ah = *reinterpret_cast<const bf16x8*>(Qb + qbase + kt * qstep);
            const __bf16* kc = Kb + kbase + kt * kstep;
#pragma unroll
            for (int t = 0; t < 16; ++t) {
                const bf16x8 bkv = *reinterpret_cast<const bf16x8*>(kc + (size_t)t * 128);
                acc[t] = __builtin_amdgcn_mfma_f32_16x16x32_bf16(ah, bkv, acc[t], 0, 0, 0);
            }
        }
        // C/D: col = l4 (key), row = quad*4 + reg. dword0 = rows {4q,4q+1},
        // dword1 = rows {4q+2,4q+3} -> planes 2q and 2q+1 at [key].
#pragma unroll
        for (int t = 0; t < 16; ++t) {
            const int key = key0 + t * 16 + l4;
            SW[(2 * quad + 0) * 2056 + key] = f2h2(acc[t][0], acc[t][1]);
            SW[(2 * quad + 1) * 2056 + key] = f2h2(acc[t][2], acc[t][3]);
        }
    }
    __syncthreads();

    // ---------------- phase 2: entmax, 2 rows per wave, interleaved ----------
    const int g  = wv >> 1;                 // rowgroup 0..3
    const int sp = wv & 1;                  // rows 4g+2sp+{0,1}

    const unsigned int* Sw = &SW[(2 * g + sp) * 2056];
    unsigned int raw[32];
#pragma unroll
    for (int c = 0; c < 32; ++c) raw[c] = Sw[c * 64 + lane];   // stride-1: no conflict

    // split into the two sub-rows' f16x2 key-pair vectors
    half2v z0[16], z1[16];
#pragma unroll
    for (int i = 0; i < 16; ++i) {
        union { unsigned int u; half2v h; } c0, c1;
        c0.u = __builtin_amdgcn_perm(raw[2 * i + 1], raw[2 * i], 0x05040100u);
        c1.u = __builtin_amdgcn_perm(raw[2 * i + 1], raw[2 * i], 0x07060302u);
        z0[i] = c0.h;
        z1[i] = c1.h;
    }

    const half2v hzero = {(_Float16)0.0f, (_Float16)0.0f};
    const half2v hone  = {(_Float16)1.0f, (_Float16)1.0f};

    // row maxes (two independent chains)
    float m0 = -1e30f, m1 = -1e30f;
#pragma unroll
    for (int i = 0; i < 16; ++i) {
        m0 = fmaxf(m0, fmaxf((float)z0[i].x, (float)z0[i].y));
        m1 = fmaxf(m1, fmaxf((float)z1[i].x, (float)z1[i].y));
    }
#pragma unroll
    for (int off = 32; off >= 1; off >>= 1) {
        m0 = fmaxf(m0, __shfl_xor(m0, off, 64));
        m1 = fmaxf(m1, __shfl_xor(m1, off, 64));
    }

    // Newton: th += (f - 512)/(2g); monotone from the left, 7 iterations
    float th0 = m0 - THETA_SPAN;
    float th1 = m1 - THETA_SPAN;
    for (int it = 0; it < 7; ++it) {
        const _Float16 t0h = (_Float16)th0;
        const _Float16 t1h = (_Float16)th1;
        const half2v n0 = {(_Float16)-t0h, (_Float16)-t0h};
        const half2v n1 = {(_Float16)-t1h, (_Float16)-t1h};
        float f0 = 0.0f, f1 = 0.0f, g0 = 0.0f, g1 = 0.0f;
#pragma unroll
        for (int i = 0; i < 16; ++i) {
            half2v d0 = z0[i] + n0;
            half2v d1 = z1[i] + n1;
            d0 = __builtin_elementwise_max(d0, hzero);
            d1 = __builtin_elementwise_max(d1, hzero);
            f0 = fdot2acc(d0, d0, f0);
            f1 = fdot2acc(d1, d1, f1);
            g0 = fdot2acc(d0, hone, g0);
            g1 = fdot2acc(d1, hone, g1);
        }
#pragma unroll
        for (int off = 32; off >= 1; off >>= 1) {
            f0 += __shfl_xor(f0, off, 64);
            f1 += __shfl_xor(f1, off, 64);
            g0 += __shfl_xor(g0, off, 64);
            g1 += __shfl_xor(g1, off, 64);
        }
        th0 += (f0 - 512.0f) / (2.0f * g0);
        th1 += (f1 - 512.0f) / (2.0f * g1);
    }

    // epilogue: p = max(s-th,0)^2 / 512, nontemporal f32 coalesced stores
    float* o0 = out + (size_t)(row0 + 4 * g + 2 * sp + 0) * SEQ + lane;
    float* o1 = out + (size_t)(row0 + 4 * g + 2 * sp + 1) * SEQ + lane;
#pragma unroll
    for (int i = 0; i < 16; ++i) {
        const float a0 = fmaxf((float)z0[i].x - th0, 0.0f);
        const float a1 = fmaxf((float)z0[i].y - th0, 0.0f);
        const float b0 = fmaxf((float)z1[i].x - th1, 0.0f);
        const float b1 = fmaxf((float)z1[i].y - th1, 0.0f);
        __builtin_nontemporal_store(a0 * a0 * (1.0f / 512.0f), o0 + (size_t)(2 * i) * 64);
        __builtin_nontemporal_store(a1 * a1 * (1.0f / 512.0f), o0 + (size_t)(2 * i + 1) * 64);
        __builtin_nontemporal_store(b0 * b0 * (1.0f / 512.0f), o1 + (size_t)(2 * i) * 64);
        __builtin_nontemporal_store(b1 * b1 * (1.0f / 512.0f), o1 + (size_t)(2 * i + 1) * 64);
    }
}

// ---------------------------------------------------------------------------
extern "C" void kernel_launch(void* const* d_in, const int* in_sizes, int n_in,
                              void* d_out, int out_size, void* d_ws, size_t ws_size,
                              hipStream_t stream) {
    const float* x_c = (const float*)d_in[0];
    const float* x_n = (const float*)d_in[1];
    const float* Wq  = (const float*)d_in[2];
    const float* bq  = (const float*)d_in[3];
    const float* Wk  = (const float*)d_in[4];
    const float* bk  = (const float*)d_in[5];
    float* out = (float*)d_out;

    char* ws = (char*)d_ws;
    unsigned short* Qbl = (unsigned short*)ws;                        // 4 MB
    unsigned short* Kbl = (unsigned short*)(ws + ((size_t)4 << 20));  // 4 MB
    unsigned int*   cnt = (unsigned int*)(ws + ((size_t)8 << 20));    // 8 ctrs

    proj_qk<<<dim3(NROWS / 64, 2), 256, 0, stream>>>(
        x_c, x_n, Wq, bq, Wk, bk, Qbl, Kbl, cnt);
    attn_fused<<<NROWS / 16, 512, 0, stream>>>(
        (const __bf16*)Qbl, (const __bf16*)Kbl, out, cnt);
}

// Round 4
// 191.647 us; speedup vs baseline: 1.9521x; 1.0449x over previous
//
#include <hip/hip_runtime.h>
#include <hip/hip_bf16.h>

#define BATCH 8
#define SEQ   2048
#define DIM   128
#define NROWS 16384                       // BATCH*SEQ
#define THETA_SPAN 22.62741699796952f     // 2*sqrt(128) = 1/c ; c^2 = 1/512

typedef __bf16    bf16x8   __attribute__((ext_vector_type(8)));
typedef float     floatx4  __attribute__((ext_vector_type(4)));
typedef _Float16  half2v   __attribute__((ext_vector_type(2)));

static __device__ __forceinline__ unsigned short f2bf(float v) {
    union { __hip_bfloat16 h; unsigned short u; } c;
    c.h = __float2bfloat16(v);
    return c.u;
}
static __device__ __forceinline__ float bf2f(unsigned short u) {
    union { unsigned int i; float f; } c;
    c.i = (unsigned int)u << 16;
    return c.f;
}
static __device__ __forceinline__ unsigned int f2h2(float a, float b) {
    union { _Float16 h; unsigned short u; } ca, cb;
    ca.h = (_Float16)a;
    cb.h = (_Float16)b;
    return (unsigned int)ca.u | ((unsigned int)cb.u << 16);
}

#if __has_builtin(__builtin_amdgcn_fdot2)
static __device__ __forceinline__ float fdot2acc(half2v a, half2v b, float c) {
    return __builtin_amdgcn_fdot2(a, b, c, false);
}
#else
static __device__ __forceinline__ float fdot2acc(half2v a, half2v b, float c) {
    return fmaf((float)a.y, (float)b.y, fmaf((float)a.x, (float)b.x, c));
}
#endif

// ---------------------------------------------------------------------------
// MFMA-based Q/K projection (baseline-verified; atomic-counter plumbing from
// round 2 removed — it was a measured regression).
// ---------------------------------------------------------------------------
__global__ void __launch_bounds__(256, 2)
proj_qk(const float* __restrict__ xq, const float* __restrict__ xn,
        const float* __restrict__ Wq, const float* __restrict__ bq,
        const float* __restrict__ Wk, const float* __restrict__ bk,
        unsigned short* __restrict__ Qb, unsigned short* __restrict__ Kb) {
    const int isK = blockIdx.y;
    const float* __restrict__ X    = isK ? xn : xq;
    const float* __restrict__ W    = isK ? Wk : Wq;
    const float* __restrict__ bias = isK ? bk : bq;

    __shared__ __align__(16) unsigned short SM[34816];
    unsigned short* XH = SM;            // 64 x 136
    unsigned short* XL = SM + 8704;     // 64 x 136
    unsigned short* WW = SM + 17408;    // 128 x 136

    const int tid  = threadIdx.x;
    const int lane = tid & 63;
    const int wv   = tid >> 6;          // 0..3
    const int l4   = lane & 15;
    const int quad = lane >> 4;         // 0..3
    const int row0 = blockIdx.x * 64;

    // ---- stage X (64x128 f32 -> bf16 hi+lo), coalesced float4 reads ----
#pragma unroll
    for (int i = 0; i < 8; ++i) {
        const int g  = tid + 256 * i;          // g < 2048
        const int r  = g >> 5;
        const int c4 = g & 31;
        const float4 xv = *reinterpret_cast<const float4*>(
            X + (size_t)(row0 + r) * DIM + 4 * c4);
        union { ushort2 v[2]; unsigned short u[4]; } hh, ll;
        const float xf[4] = {xv.x, xv.y, xv.z, xv.w};
#pragma unroll
        for (int j = 0; j < 4; ++j) {
            const unsigned short h = f2bf(xf[j]);
            hh.u[j] = h;
            ll.u[j] = f2bf(xf[j] - bf2f(h));
        }
        *reinterpret_cast<uint2*>(&XH[r * 136 + 4 * c4]) =
            *reinterpret_cast<uint2*>(hh.u);
        *reinterpret_cast<uint2*>(&XL[r * 136 + 4 * c4]) =
            *reinterpret_cast<uint2*>(ll.u);
    }
    // ---- stage W (128x128 f32 -> bf16), coalesced ----
#pragma unroll
    for (int i = 0; i < 16; ++i) {
        const int g  = tid + 256 * i;          // g < 4096
        const int d  = g >> 5;
        const int c4 = g & 31;
        const float4 wvv = *reinterpret_cast<const float4*>(
            W + (size_t)d * DIM + 4 * c4);
        union { uint2 v; unsigned short u[4]; } pw;
        pw.u[0] = f2bf(wvv.x); pw.u[1] = f2bf(wvv.y);
        pw.u[2] = f2bf(wvv.z); pw.u[3] = f2bf(wvv.w);
        *reinterpret_cast<uint2*>(&WW[d * 136 + 4 * c4]) = pw.v;
    }
    __syncthreads();

    // ---- MFMA: acc[mt][reg] = value of (row = wv*16+l4, d = mt*16+quad*4+reg)
    floatx4 acc[8];
    const floatx4 zerov = {};
#pragma unroll
    for (int mt = 0; mt < 8; ++mt) acc[mt] = zerov;

#pragma unroll
    for (int kt = 0; kt < 4; ++kt) {
        const int koff = kt * 32 + quad * 8;
        const bf16x8 xh = *reinterpret_cast<const bf16x8*>(
            &XH[(wv * 16 + l4) * 136 + koff]);
        const bf16x8 xl = *reinterpret_cast<const bf16x8*>(
            &XL[(wv * 16 + l4) * 136 + koff]);
#pragma unroll
        for (int mt = 0; mt < 8; ++mt) {
            const bf16x8 wf = *reinterpret_cast<const bf16x8*>(
                &WW[(mt * 16 + l4) * 136 + koff]);
            acc[mt] = __builtin_amdgcn_mfma_f32_16x16x32_bf16(wf, xh, acc[mt], 0, 0, 0);
            acc[mt] = __builtin_amdgcn_mfma_f32_16x16x32_bf16(wf, xl, acc[mt], 0, 0, 0);
        }
    }

    // ---- epilogue: +bias, round once to bf16, pack into XH plane (own rows)
    const int erow = wv * 16 + l4;      // this lane's output row
#pragma unroll
    for (int mt = 0; mt < 8; ++mt) {
        const float4 bv = *reinterpret_cast<const float4*>(bias + mt * 16 + quad * 4);
        const float bf[4] = {bv.x, bv.y, bv.z, bv.w};
        union { uint2 v; unsigned short u[4]; } hh;
#pragma unroll
        for (int r = 0; r < 4; ++r) hh.u[r] = f2bf(acc[mt][r] + bf[r]);
        *reinterpret_cast<uint2*>(&XH[erow * 136 + mt * 16 + quad * 4]) = hh.v;
    }
    __syncthreads();

    // ---- readback + coalesced global stores (verified layouts) ----
    const int l    = tid & 15;
    const int kthi = tid >> 4;          // 0..15
    if (!isK) {
#pragma unroll
        for (int rr = 0; rr < 4; ++rr) {
            const int row = l + 16 * rr;
            const uint4 ph = *reinterpret_cast<const uint4*>(&XH[row * 136 + kthi * 8]);
            const size_t base = ((size_t)kthi * NROWS + row0 + row) * 8;
            *reinterpret_cast<uint4*>(Qb + base) = ph;
        }
    } else {
#pragma unroll
        for (int rr = 0; rr < 4; ++rr) {
            const int row = l + 16 * rr;
            const int grow = row0 + row;
            const int b    = grow >> 11;
            const int key  = grow & (SEQ - 1);
            const uint4 pk = *reinterpret_cast<const uint4*>(&XH[row * 136 + kthi * 8]);
            const size_t base = (((size_t)(b * 16) + kthi) * SEQ + key) * 8;
            *reinterpret_cast<uint4*>(Kb + base) = pk;
        }
    }
}

// ---------------------------------------------------------------------------
// FUSED scores + entmax — 32 Q-ROWS PER BLOCK (was 16). Issued K traffic is
// (NROWS/rows_per_block) x 512 KB: 32 rows halves it 512 MB -> 256 MB,
// independent of cache scheduling (rounds 0/2/3 showed locality tricks are
// not controllable). 1024 threads / 16 waves / 1 block per CU (LDS 131.6 KB),
// still 4 waves per SIMD. Phase 1: wave w covers keys [128w,128w+128) x all
// 32 rows (2 row-groups x 8 key-tiles x kt4 = 64 MFMA/wave, same 64-VGPR
// acc). Plane p (of 16) holds rows {2p,2p+1} as f16 pairs -> phase 2 is the
// verified per-wave entmax with plane index = wv, rows row0+2wv+{0,1}.
// Bank math: score writes 2-way (free), reads 2-way (free), as before.
// ---------------------------------------------------------------------------
__global__ void __launch_bounds__(1024, 4)
attn_fused(const __bf16* __restrict__ Qb, const __bf16* __restrict__ Kb,
           float* __restrict__ out) {
    __shared__ unsigned int SW[16 * 2056];
    const int tid  = threadIdx.x;
    const int wv   = tid >> 6;              // 0..15
    const int lane = tid & 63;
    const int l4   = lane & 15;
    const int quad = lane >> 4;             // 0..3
    const int b    = blockIdx.x >> 6;       // batch
    const int rb   = blockIdx.x & 63;       // 32-row tile within batch
    const int row0 = (b << 11) + (rb << 5);
    const int key0 = wv << 7;               // 128-key stripe per wave

    // ---------------- phase 1: MFMA scores -> LDS subplanes ----------------
    {
        floatx4 acc[2][8];
        const floatx4 zerov = {};
#pragma unroll
        for (int rg = 0; rg < 2; ++rg)
#pragma unroll
            for (int t = 0; t < 8; ++t) acc[rg][t] = zerov;

        const size_t qbase0 = ((size_t)quad * NROWS + row0 + l4) * 8;
        const size_t qbase1 = ((size_t)quad * NROWS + row0 + 16 + l4) * 8;
        const size_t kbase  = (((size_t)(b * 16) + quad) * SEQ + key0 + l4) * 8;
        const size_t qstep  = (size_t)4 * NROWS * 8;   // kt -> kt+1
        const size_t kstep  = (size_t)4 * SEQ * 8;

#pragma unroll
        for (int kt = 0; kt < 4; ++kt) {
            const bf16x8 ah0 = *reinterpret_cast<const bf16x8*>(Qb + qbase0 + kt * qstep);
            const bf16x8 ah1 = *reinterpret_cast<const bf16x8*>(Qb + qbase1 + kt * qstep);
            const __bf16* kc = Kb + kbase + kt * kstep;
#pragma unroll
            for (int t = 0; t < 8; ++t) {
                const bf16x8 bkv = *reinterpret_cast<const bf16x8*>(kc + (size_t)t * 128);
                acc[0][t] = __builtin_amdgcn_mfma_f32_16x16x32_bf16(ah0, bkv, acc[0][t], 0, 0, 0);
                acc[1][t] = __builtin_amdgcn_mfma_f32_16x16x32_bf16(ah1, bkv, acc[1][t], 0, 0, 0);
            }
        }
        // C/D: col = l4 (key), row-within-group = quad*4 + reg.
        // Row pair {16rg+4q, +1} -> plane 8rg+2q+0; {+2,+3} -> plane 8rg+2q+1.
#pragma unroll
        for (int rg = 0; rg < 2; ++rg)
#pragma unroll
            for (int t = 0; t < 8; ++t) {
                const int key = key0 + t * 16 + l4;
                SW[(8 * rg + 2 * quad + 0) * 2056 + key] = f2h2(acc[rg][t][0], acc[rg][t][1]);
                SW[(8 * rg + 2 * quad + 1) * 2056 + key] = f2h2(acc[rg][t][2], acc[rg][t][3]);
            }
    }
    __syncthreads();

    // ---------------- phase 2: entmax, 2 rows per wave (plane = wv) --------
    const unsigned int* Sw = &SW[wv * 2056];
    unsigned int raw[32];
#pragma unroll
    for (int c = 0; c < 32; ++c) raw[c] = Sw[c * 64 + lane];   // 2-way: free

    // split into the two sub-rows' f16x2 key-pair vectors
    half2v z0[16], z1[16];
#pragma unroll
    for (int i = 0; i < 16; ++i) {
        union { unsigned int u; half2v h; } c0, c1;
        c0.u = __builtin_amdgcn_perm(raw[2 * i + 1], raw[2 * i], 0x05040100u);
        c1.u = __builtin_amdgcn_perm(raw[2 * i + 1], raw[2 * i], 0x07060302u);
        z0[i] = c0.h;
        z1[i] = c1.h;
    }

    const half2v hzero = {(_Float16)0.0f, (_Float16)0.0f};
    const half2v hone  = {(_Float16)1.0f, (_Float16)1.0f};

    // row maxes (two independent chains)
    float m0 = -1e30f, m1 = -1e30f;
#pragma unroll
    for (int i = 0; i < 16; ++i) {
        m0 = fmaxf(m0, fmaxf((float)z0[i].x, (float)z0[i].y));
        m1 = fmaxf(m1, fmaxf((float)z1[i].x, (float)z1[i].y));
    }
#pragma unroll
    for (int off = 32; off >= 1; off >>= 1) {
        m0 = fmaxf(m0, __shfl_xor(m0, off, 64));
        m1 = fmaxf(m1, __shfl_xor(m1, off, 64));
    }

    // Newton: th += (f - 512)/(2g); monotone from the left, 7 iterations
    float th0 = m0 - THETA_SPAN;
    float th1 = m1 - THETA_SPAN;
    for (int it = 0; it < 7; ++it) {
        const _Float16 t0h = (_Float16)th0;
        const _Float16 t1h = (_Float16)th1;
        const half2v n0 = {(_Float16)-t0h, (_Float16)-t0h};
        const half2v n1 = {(_Float16)-t1h, (_Float16)-t1h};
        float f0 = 0.0f, f1 = 0.0f, g0 = 0.0f, g1 = 0.0f;
#pragma unroll
        for (int i = 0; i < 16; ++i) {
            half2v d0 = z0[i] + n0;
            half2v d1 = z1[i] + n1;
            d0 = __builtin_elementwise_max(d0, hzero);
            d1 = __builtin_elementwise_max(d1, hzero);
            f0 = fdot2acc(d0, d0, f0);
            f1 = fdot2acc(d1, d1, f1);
            g0 = fdot2acc(d0, hone, g0);
            g1 = fdot2acc(d1, hone, g1);
        }
#pragma unroll
        for (int off = 32; off >= 1; off >>= 1) {
            f0 += __shfl_xor(f0, off, 64);
            f1 += __shfl_xor(f1, off, 64);
            g0 += __shfl_xor(g0, off, 64);
            g1 += __shfl_xor(g1, off, 64);
        }
        th0 += (f0 - 512.0f) / (2.0f * g0);
        th1 += (f1 - 512.0f) / (2.0f * g1);
    }

    // epilogue: p = max(s-th,0)^2 / 512, nontemporal f32 coalesced stores
    float* o0 = out + (size_t)(row0 + 2 * wv + 0) * SEQ + lane;
    float* o1 = out + (size_t)(row0 + 2 * wv + 1) * SEQ + lane;
#pragma unroll
    for (int i = 0; i < 16; ++i) {
        const float a0 = fmaxf((float)z0[i].x - th0, 0.0f);
        const float a1 = fmaxf((float)z0[i].y - th0, 0.0f);
        const float b0 = fmaxf((float)z1[i].x - th1, 0.0f);
        const float b1 = fmaxf((float)z1[i].y - th1, 0.0f);
        __builtin_nontemporal_store(a0 * a0 * (1.0f / 512.0f), o0 + (size_t)(2 * i) * 64);
        __builtin_nontemporal_store(a1 * a1 * (1.0f / 512.0f), o0 + (size_t)(2 * i + 1) * 64);
        __builtin_nontemporal_store(b0 * b0 * (1.0f / 512.0f), o1 + (size_t)(2 * i) * 64);
        __builtin_nontemporal_store(b1 * b1 * (1.0f / 512.0f), o1 + (size_t)(2 * i + 1) * 64);
    }
}

// ---------------------------------------------------------------------------
extern "C" void kernel_launch(void* const* d_in, const int* in_sizes, int n_in,
                              void* d_out, int out_size, void* d_ws, size_t ws_size,
                              hipStream_t stream) {
    const float* x_c = (const float*)d_in[0];
    const float* x_n = (const float*)d_in[1];
    const float* Wq  = (const float*)d_in[2];
    const float* bq  = (const float*)d_in[3];
    const float* Wk  = (const float*)d_in[4];
    const float* bk  = (const float*)d_in[5];
    float* out = (float*)d_out;

    char* ws = (char*)d_ws;
    unsigned short* Qbl = (unsigned short*)ws;                        // 4 MB
    unsigned short* Kbl = (unsigned short*)(ws + ((size_t)4 << 20));  // 4 MB

    proj_qk<<<dim3(NROWS / 64, 2), 256, 0, stream>>>(
        x_c, x_n, Wq, bq, Wk, bk, Qbl, Kbl);
    attn_fused<<<NROWS / 32, 1024, 0, stream>>>(
        (const __bf16*)Qbl, (const __bf16*)Kbl, out);
}

// Round 5
// 185.568 us; speedup vs baseline: 2.0161x; 1.0328x over previous
//
#include <hip/hip_runtime.h>
#include <hip/hip_bf16.h>

#define BATCH 8
#define SEQ   2048
#define DIM   128
#define NROWS 16384                       // BATCH*SEQ
#define THETA_SPAN 22.62741699796952f     // 2*sqrt(128) = 1/c ; c^2 = 1/512

typedef __bf16    bf16x8   __attribute__((ext_vector_type(8)));
typedef float     floatx4  __attribute__((ext_vector_type(4)));
typedef _Float16  half2v   __attribute__((ext_vector_type(2)));

static __device__ __forceinline__ unsigned short f2bf(float v) {
    union { __hip_bfloat16 h; unsigned short u; } c;
    c.h = __float2bfloat16(v);
    return c.u;
}
static __device__ __forceinline__ float bf2f(unsigned short u) {
    union { unsigned int i; float f; } c;
    c.i = (unsigned int)u << 16;
    return c.f;
}
static __device__ __forceinline__ unsigned int f2h2(float a, float b) {
    union { _Float16 h; unsigned short u; } ca, cb;
    ca.h = (_Float16)a;
    cb.h = (_Float16)b;
    return (unsigned int)ca.u | ((unsigned int)cb.u << 16);
}

#if __has_builtin(__builtin_amdgcn_fdot2)
static __device__ __forceinline__ float fdot2acc(half2v a, half2v b, float c) {
    return __builtin_amdgcn_fdot2(a, b, c, false);
}
#else
static __device__ __forceinline__ float fdot2acc(half2v a, half2v b, float c) {
    return fmaf((float)a.y, (float)b.y, fmaf((float)a.x, (float)b.x, c));
}
#endif

// ---------------------------------------------------------------------------
// MFMA-based Q/K projection (baseline-verified, unchanged).
// ---------------------------------------------------------------------------
__global__ void __launch_bounds__(256, 2)
proj_qk(const float* __restrict__ xq, const float* __restrict__ xn,
        const float* __restrict__ Wq, const float* __restrict__ bq,
        const float* __restrict__ Wk, const float* __restrict__ bk,
        unsigned short* __restrict__ Qb, unsigned short* __restrict__ Kb) {
    const int isK = blockIdx.y;
    const float* __restrict__ X    = isK ? xn : xq;
    const float* __restrict__ W    = isK ? Wk : Wq;
    const float* __restrict__ bias = isK ? bk : bq;

    __shared__ __align__(16) unsigned short SM[34816];
    unsigned short* XH = SM;            // 64 x 136
    unsigned short* XL = SM + 8704;     // 64 x 136
    unsigned short* WW = SM + 17408;    // 128 x 136

    const int tid  = threadIdx.x;
    const int lane = tid & 63;
    const int wv   = tid >> 6;          // 0..3
    const int l4   = lane & 15;
    const int quad = lane >> 4;         // 0..3
    const int row0 = blockIdx.x * 64;

    // ---- stage X (64x128 f32 -> bf16 hi+lo), coalesced float4 reads ----
#pragma unroll
    for (int i = 0; i < 8; ++i) {
        const int g  = tid + 256 * i;          // g < 2048
        const int r  = g >> 5;
        const int c4 = g & 31;
        const float4 xv = *reinterpret_cast<const float4*>(
            X + (size_t)(row0 + r) * DIM + 4 * c4);
        union { ushort2 v[2]; unsigned short u[4]; } hh, ll;
        const float xf[4] = {xv.x, xv.y, xv.z, xv.w};
#pragma unroll
        for (int j = 0; j < 4; ++j) {
            const unsigned short h = f2bf(xf[j]);
            hh.u[j] = h;
            ll.u[j] = f2bf(xf[j] - bf2f(h));
        }
        *reinterpret_cast<uint2*>(&XH[r * 136 + 4 * c4]) =
            *reinterpret_cast<uint2*>(hh.u);
        *reinterpret_cast<uint2*>(&XL[r * 136 + 4 * c4]) =
            *reinterpret_cast<uint2*>(ll.u);
    }
    // ---- stage W (128x128 f32 -> bf16), coalesced ----
#pragma unroll
    for (int i = 0; i < 16; ++i) {
        const int g  = tid + 256 * i;          // g < 4096
        const int d  = g >> 5;
        const int c4 = g & 31;
        const float4 wvv = *reinterpret_cast<const float4*>(
            W + (size_t)d * DIM + 4 * c4);
        union { uint2 v; unsigned short u[4]; } pw;
        pw.u[0] = f2bf(wvv.x); pw.u[1] = f2bf(wvv.y);
        pw.u[2] = f2bf(wvv.z); pw.u[3] = f2bf(wvv.w);
        *reinterpret_cast<uint2*>(&WW[d * 136 + 4 * c4]) = pw.v;
    }
    __syncthreads();

    // ---- MFMA: acc[mt][reg] = value of (row = wv*16+l4, d = mt*16+quad*4+reg)
    floatx4 acc[8];
    const floatx4 zerov = {};
#pragma unroll
    for (int mt = 0; mt < 8; ++mt) acc[mt] = zerov;

#pragma unroll
    for (int kt = 0; kt < 4; ++kt) {
        const int koff = kt * 32 + quad * 8;
        const bf16x8 xh = *reinterpret_cast<const bf16x8*>(
            &XH[(wv * 16 + l4) * 136 + koff]);
        const bf16x8 xl = *reinterpret_cast<const bf16x8*>(
            &XL[(wv * 16 + l4) * 136 + koff]);
#pragma unroll
        for (int mt = 0; mt < 8; ++mt) {
            const bf16x8 wf = *reinterpret_cast<const bf16x8*>(
                &WW[(mt * 16 + l4) * 136 + koff]);
            acc[mt] = __builtin_amdgcn_mfma_f32_16x16x32_bf16(wf, xh, acc[mt], 0, 0, 0);
            acc[mt] = __builtin_amdgcn_mfma_f32_16x16x32_bf16(wf, xl, acc[mt], 0, 0, 0);
        }
    }

    // ---- epilogue: +bias, round once to bf16, pack into XH plane (own rows)
    const int erow = wv * 16 + l4;      // this lane's output row
#pragma unroll
    for (int mt = 0; mt < 8; ++mt) {
        const float4 bv = *reinterpret_cast<const float4*>(bias + mt * 16 + quad * 4);
        const float bf[4] = {bv.x, bv.y, bv.z, bv.w};
        union { uint2 v; unsigned short u[4]; } hh;
#pragma unroll
        for (int r = 0; r < 4; ++r) hh.u[r] = f2bf(acc[mt][r] + bf[r]);
        *reinterpret_cast<uint2*>(&XH[erow * 136 + mt * 16 + quad * 4]) = hh.v;
    }
    __syncthreads();

    // ---- readback + coalesced global stores (verified layouts) ----
    const int l    = tid & 15;
    const int kthi = tid >> 4;          // 0..15
    if (!isK) {
#pragma unroll
        for (int rr = 0; rr < 4; ++rr) {
            const int row = l + 16 * rr;
            const uint4 ph = *reinterpret_cast<const uint4*>(&XH[row * 136 + kthi * 8]);
            const size_t base = ((size_t)kthi * NROWS + row0 + row) * 8;
            *reinterpret_cast<uint4*>(Qb + base) = ph;
        }
    } else {
#pragma unroll
        for (int rr = 0; rr < 4; ++rr) {
            const int row = l + 16 * rr;
            const int grow = row0 + row;
            const int b    = grow >> 11;
            const int key  = grow & (SEQ - 1);
            const uint4 pk = *reinterpret_cast<const uint4*>(&XH[row * 136 + kthi * 8]);
            const size_t base = (((size_t)(b * 16) + kthi) * SEQ + key) * 8;
            *reinterpret_cast<uint4*>(Kb + base) = pk;
        }
    }
}

// ---------------------------------------------------------------------------
// FUSED scores + entmax — r1 structure (16 rows/block, 512 thr, 1024 blocks,
// best measured) with phase-1 restructured for LOAD-PIPELINE DEPTH:
//  (a) key dim split into two halves of 8 tiles -> acc is 32 regs (was 64),
//      freeing ~64 VGPR so a full kt's K loads (and the next kt's) can be
//      in flight instead of recycling staging registers at the 128-reg
//      occupancy cliff (r2 profile: all pipes idle -> latency-bound).
//  (b) all 4 Q fragments hoisted out of the kt loop (16 VGPR, loaded once).
//  (c) wave->key-stripe assignment rotated by blockIdx (free): decorrelates
//      1024 blocks lockstep-sweeping identical K addresses. Score layout,
//      phase 2, and all verified index math unchanged.
// ---------------------------------------------------------------------------
__global__ void __launch_bounds__(512, 4)
attn_fused(const __bf16* __restrict__ Qb, const __bf16* __restrict__ Kb,
           float* __restrict__ out) {
    __shared__ unsigned int SW[8 * 2056];
    const int tid  = threadIdx.x;
    const int wv   = tid >> 6;              // 0..7
    const int lane = tid & 63;
    const int l4   = lane & 15;
    const int quad = lane >> 4;             // 0..3
    const int row0 = blockIdx.x * 16;
    const int b    = row0 >> 11;
    const int key0 = ((wv + (int)blockIdx.x) & 7) << 8;   // rotated stripe

    // ---------------- phase 1: MFMA scores -> LDS subplanes ----------------
    {
        const size_t qbase = ((size_t)quad * NROWS + row0 + l4) * 8;
        const size_t kbase = (((size_t)(b * 16) + quad) * SEQ + key0 + l4) * 8;
        const size_t qstep = (size_t)4 * NROWS * 8;   // kt -> kt+1
        const size_t kstep = (size_t)4 * SEQ * 8;

        bf16x8 ah[4];
#pragma unroll
        for (int kt = 0; kt < 4; ++kt)
            ah[kt] = *reinterpret_cast<const bf16x8*>(Qb + qbase + kt * qstep);

#pragma unroll
        for (int half = 0; half < 2; ++half) {
            floatx4 acc[8];
            const floatx4 zerov = {};
#pragma unroll
            for (int t = 0; t < 8; ++t) acc[t] = zerov;

#pragma unroll
            for (int kt = 0; kt < 4; ++kt) {
                const __bf16* kc = Kb + kbase + kt * kstep + (size_t)(half * 8) * 128;
#pragma unroll
                for (int t = 0; t < 8; ++t) {
                    const bf16x8 bkv = *reinterpret_cast<const bf16x8*>(kc + (size_t)t * 128);
                    acc[t] = __builtin_amdgcn_mfma_f32_16x16x32_bf16(ah[kt], bkv, acc[t], 0, 0, 0);
                }
            }
            // C/D: col = l4 (key), row = quad*4 + reg. dword0 = rows {4q,4q+1},
            // dword1 = rows {4q+2,4q+3} -> planes 2q and 2q+1 at [key].
#pragma unroll
            for (int t = 0; t < 8; ++t) {
                const int key = key0 + half * 128 + t * 16 + l4;
                SW[(2 * quad + 0) * 2056 + key] = f2h2(acc[t][0], acc[t][1]);
                SW[(2 * quad + 1) * 2056 + key] = f2h2(acc[t][2], acc[t][3]);
            }
        }
    }
    __syncthreads();

    // ---------------- phase 2: entmax, 2 rows per wave, interleaved ----------
    const int g  = wv >> 1;                 // rowgroup 0..3
    const int sp = wv & 1;                  // rows 4g+2sp+{0,1}

    const unsigned int* Sw = &SW[(2 * g + sp) * 2056];
    unsigned int raw[32];
#pragma unroll
    for (int c = 0; c < 32; ++c) raw[c] = Sw[c * 64 + lane];   // stride-1: no conflict

    // split into the two sub-rows' f16x2 key-pair vectors
    half2v z0[16], z1[16];
#pragma unroll
    for (int i = 0; i < 16; ++i) {
        union { unsigned int u; half2v h; } c0, c1;
        c0.u = __builtin_amdgcn_perm(raw[2 * i + 1], raw[2 * i], 0x05040100u);
        c1.u = __builtin_amdgcn_perm(raw[2 * i + 1], raw[2 * i], 0x07060302u);
        z0[i] = c0.h;
        z1[i] = c1.h;
    }

    const half2v hzero = {(_Float16)0.0f, (_Float16)0.0f};
    const half2v hone  = {(_Float16)1.0f, (_Float16)1.0f};

    // row maxes (two independent chains)
    float m0 = -1e30f, m1 = -1e30f;
#pragma unroll
    for (int i = 0; i < 16; ++i) {
        m0 = fmaxf(m0, fmaxf((float)z0[i].x, (float)z0[i].y));
        m1 = fmaxf(m1, fmaxf((float)z1[i].x, (float)z1[i].y));
    }
#pragma unroll
    for (int off = 32; off >= 1; off >>= 1) {
        m0 = fmaxf(m0, __shfl_xor(m0, off, 64));
        m1 = fmaxf(m1, __shfl_xor(m1, off, 64));
    }

    // Newton: th += (f - 512)/(2g); monotone from the left, 7 iterations
    float th0 = m0 - THETA_SPAN;
    float th1 = m1 - THETA_SPAN;
    for (int it = 0; it < 7; ++it) {
        const _Float16 t0h = (_Float16)th0;
        const _Float16 t1h = (_Float16)th1;
        const half2v n0 = {(_Float16)-t0h, (_Float16)-t0h};
        const half2v n1 = {(_Float16)-t1h, (_Float16)-t1h};
        float f0 = 0.0f, f1 = 0.0f, g0 = 0.0f, g1 = 0.0f;
#pragma unroll
        for (int i = 0; i < 16; ++i) {
            half2v d0 = z0[i] + n0;
            half2v d1 = z1[i] + n1;
            d0 = __builtin_elementwise_max(d0, hzero);
            d1 = __builtin_elementwise_max(d1, hzero);
            f0 = fdot2acc(d0, d0, f0);
            f1 = fdot2acc(d1, d1, f1);
            g0 = fdot2acc(d0, hone, g0);
            g1 = fdot2acc(d1, hone, g1);
        }
#pragma unroll
        for (int off = 32; off >= 1; off >>= 1) {
            f0 += __shfl_xor(f0, off, 64);
            f1 += __shfl_xor(f1, off, 64);
            g0 += __shfl_xor(g0, off, 64);
            g1 += __shfl_xor(g1, off, 64);
        }
        th0 += (f0 - 512.0f) / (2.0f * g0);
        th1 += (f1 - 512.0f) / (2.0f * g1);
    }

    // epilogue: p = max(s-th,0)^2 / 512, nontemporal f32 coalesced stores
    float* o0 = out + (size_t)(row0 + 4 * g + 2 * sp + 0) * SEQ + lane;
    float* o1 = out + (size_t)(row0 + 4 * g + 2 * sp + 1) * SEQ + lane;
#pragma unroll
    for (int i = 0; i < 16; ++i) {
        const float a0 = fmaxf((float)z0[i].x - th0, 0.0f);
        const float a1 = fmaxf((float)z0[i].y - th0, 0.0f);
        const float b0 = fmaxf((float)z1[i].x - th1, 0.0f);
        const float b1 = fmaxf((float)z1[i].y - th1, 0.0f);
        __builtin_nontemporal_store(a0 * a0 * (1.0f / 512.0f), o0 + (size_t)(2 * i) * 64);
        __builtin_nontemporal_store(a1 * a1 * (1.0f / 512.0f), o0 + (size_t)(2 * i + 1) * 64);
        __builtin_nontemporal_store(b0 * b0 * (1.0f / 512.0f), o1 + (size_t)(2 * i) * 64);
        __builtin_nontemporal_store(b1 * b1 * (1.0f / 512.0f), o1 + (size_t)(2 * i + 1) * 64);
    }
}

// ---------------------------------------------------------------------------
extern "C" void kernel_launch(void* const* d_in, const int* in_sizes, int n_in,
                              void* d_out, int out_size, void* d_ws, size_t ws_size,
                              hipStream_t stream) {
    const float* x_c = (const float*)d_in[0];
    const float* x_n = (const float*)d_in[1];
    const float* Wq  = (const float*)d_in[2];
    const float* bq  = (const float*)d_in[3];
    const float* Wk  = (const float*)d_in[4];
    const float* bk  = (const float*)d_in[5];
    float* out = (float*)d_out;

    char* ws = (char*)d_ws;
    unsigned short* Qbl = (unsigned short*)ws;                        // 4 MB
    unsigned short* Kbl = (unsigned short*)(ws + ((size_t)4 << 20));  // 4 MB

    proj_qk<<<dim3(NROWS / 64, 2), 256, 0, stream>>>(
        x_c, x_n, Wq, bq, Wk, bk, Qbl, Kbl);
    attn_fused<<<NROWS / 16, 512, 0, stream>>>(
        (const __bf16*)Qbl, (const __bf16*)Kbl, out);
}